// Round 8
// baseline (305.830 us; speedup 1.0000x reference)
//
#include <hip/hip_runtime.h>
#include <hip/hip_bf16.h>
#include <stdint.h>

typedef unsigned short u16;
typedef __attribute__((ext_vector_type(8))) short bf16x8;
typedef __attribute__((ext_vector_type(4))) float f32x4;
typedef __attribute__((ext_vector_type(4))) uint32_t u32x4;

__device__ inline u16 f2bf(float f) {
  union { float f; uint32_t u; } v; v.f = f;
  uint32_t u = v.u;
  u += 0x7FFFu + ((u >> 16) & 1u);
  return (u16)(u >> 16);
}
__device__ inline uint32_t pkbf(float a, float b) {
  union { __hip_bfloat162 h; uint32_t u; } c;
  c.h = __float22bfloat162_rn(float2{a, b});
  return c.u;
}
__device__ inline float bf2f(u16 h) {
  union { uint32_t u; float f; } v; v.u = (uint32_t)h << 16; return v.f;
}
__device__ inline void gl_lds16(const void* g, void* s) {
  __builtin_amdgcn_global_load_lds(
      (const __attribute__((address_space(1))) void*)(uintptr_t)(g),
      (__attribute__((address_space(3))) void*)(uint32_t)(uintptr_t)(s),
      16, 0, 0);
}

// ---- prolog: eig partial means (0..63) + x transpose (64..319)
//      + VT weight fold (320..703) + cvec/out-init (704..767)
__global__ __launch_bounds__(256) void k_pre(
    const float* __restrict__ eig, const float* __restrict__ x,
    const float* __restrict__ WS, const float* __restrict__ WM,
    const float* __restrict__ Ww, const float* __restrict__ bS,
    const float* __restrict__ bM, const float* __restrict__ bw,
    float* __restrict__ part, u16* __restrict__ xT,
    u16* __restrict__ VT, float* __restrict__ outp) {
  const int bid = blockIdx.x, t = threadIdx.x;
  __shared__ float red[256];
  __shared__ uint32_t L[64][33];
  if (bid < 64) {
    const int b = bid >> 5, chunk = bid & 31;
    const int d = t & 127, half = t >> 7;
    const float* p = eig + ((long)b * 4096 + chunk * 128 + half) * 128 + d;
    float s = 0.0f;
    for (int i = 0; i < 64; i++) s += p[(long)i * 256];
    red[t] = s;
    __syncthreads();
    if (t < 128) part[((long)b * 32 + chunk) * 128 + d] = red[t] + red[t + 128];
    return;
  }
  if (bid < 320) {
    // x fp32 [4096][128] -> xT bf16 [128][4096], 64x64 tiles
    const int q = bid - 64;
    const int b = q >> 7, rem = q & 127;
    const int tr = rem & 63, tc = rem >> 6;
    const float* I = x + (long)b * 524288;
    u16* O = xT + (long)b * 524288;
    const int r = t >> 2, cq = (t & 3) * 4;
    const float* src = I + (long)(tr * 64 + r) * 128 + tc * 64;
#pragma unroll
    for (int i = 0; i < 4; i++) {
      const float4 f = *(const float4*)(src + cq + 16 * i);
      const int c = cq + 16 * i;
      L[r][(c >> 1)]     = pkbf(f.x, f.y);
      L[r][(c >> 1) + 1] = pkbf(f.z, f.w);
    }
    __syncthreads();
    const int r0 = (t & 7) * 8;
#pragma unroll
    for (int p = 0; p < 2; p++) {
      const int c = (t >> 3) + 32 * p;
      uint32_t w[4];
#pragma unroll
      for (int i = 0; i < 4; i++) {
        const uint32_t w0 = L[r0 + 2 * i][c >> 1];
        const uint32_t w1 = L[r0 + 2 * i + 1][c >> 1];
        const u16 v0 = (c & 1) ? (u16)(w0 >> 16) : (u16)(w0 & 0xffff);
        const u16 v1 = (c & 1) ? (u16)(w1 >> 16) : (u16)(w1 & 0xffff);
        w[i] = (uint32_t)v0 | ((uint32_t)v1 << 16);
      }
      u32x4* dst = (u32x4*)(O + (long)(tc * 64 + c) * 4096 + tr * 64 + r0);
      *dst = u32x4{w[0], w[1], w[2], w[3]};
    }
    return;
  }
  if (bid < 704) {
    // VT[e][f*128+d] = (F_f @ Ww)[d][e]; 2 q per block
    const int q = (bid - 320) * 2 + (t >> 7);
    const int e = t & 127;
    const int f = q >> 7, d = q & 127;
    const float* Frow = (f == 0) ? (WS + d * 128) : (WM + ((long)(f - 1) * 128 + d) * 128);
    float s = 0.0f;
    for (int k = 0; k < 128; k++) s += Frow[k] * Ww[k * 128 + e];
    VT[(long)e * 768 + f * 128 + d] = f2bf(s);
    return;
  }
  // blocks 704..767: compute cvec (redundantly) and init a 16384-float slice
  // of d_out with it; GEMM3 atomically accumulates on top.
  {
    const int q2 = bid - 704;  // 0..63
    __shared__ float cv[128];
    if (t < 128) {
      float s = bw[t];
      for (int k = 0; k < 128; k++) {
        float tv = bS[k];
#pragma unroll
        for (int j = 0; j < 5; j++) tv += bM[j * 128 + k];
        s += tv * Ww[k * 128 + t];
      }
      cv[t] = s;
    }
    __syncthreads();
    float* O = outp + (long)q2 * 16384;
#pragma unroll
    for (int i = 0; i < 16; i++) {
      const int idx4 = i * 256 + t;
      const int e0 = (idx4 * 4) & 127;
      float4 v = {cv[e0], cv[e0 + 1], cv[e0 + 2], cv[e0 + 3]};
      *(float4*)(O + (long)idx4 * 4) = v;
    }
  }
}

// ---- GEMM1: xs16[ks][b][n][d] = bf16 partial sum_m U[m][n] * x[m][d]
// A = xT bf16 [d][m] via gl_lds; B = U fp32 [m][n] transposing stage (pad-17),
// register-prefetched. tn==32 blocks (ks==0) compute pooled coefficients.
__global__ __launch_bounds__(256) void k_gemm1(
    const u16* __restrict__ xT, const float* __restrict__ U,
    const float* __restrict__ part,
    const float* __restrict__ Wa, const float* __restrict__ ba,
    const float* __restrict__ Wb, const float* __restrict__ bb_,
    const float* __restrict__ Ws, const float* __restrict__ bs,
    u16* __restrict__ xs16, float* __restrict__ coeff) {
  const int tn = blockIdx.x, ks = blockIdx.y, bb = blockIdx.z;
  const int tid = threadIdx.x;
  __shared__ float sd[128];
  __shared__ __align__(16) u16 As[128 * 32];
  __shared__ __align__(16) u16 Bs[128 * 34 + 64];
  if (tn == 32) {
    if (ks != 0) return;
    if (tid < 128) {
      float s = 0.0f;
      for (int c = 0; c < 32; c++) s += part[((long)bb * 32 + c) * 128 + tid];
      sd[tid] = s * (1.0f / 4096.0f);
    }
    __syncthreads();
    if (tid >= 15) return;
    const int kind = tid / 5, r = tid % 5;
    const float* W = (kind == 0) ? Wa : ((kind == 1) ? Wb : Ws);
    float v = 0.0f;
    for (int d = 0; d < 128; d++) v += sd[d] * W[d * 5 + r];
    v += (kind == 0) ? ba[r] : ((kind == 1) ? bb_[r] : bs[r]);
    if (kind == 2) v = 5.0f / (1.0f + __expf(-v));
    coeff[bb * 16 + kind * 5 + r] = v;
    return;
  }
  const int wave = tid >> 6, lane = tid & 63;
  const int wm = (wave >> 1) * 64, wn = (wave & 1) * 64;
  f32x4 acc[4][4];
#pragma unroll
  for (int i = 0; i < 4; i++)
#pragma unroll
    for (int j = 0; j < 4; j++)
#pragma unroll
      for (int r = 0; r < 4; r++) acc[i][j][r] = 0.0f;
  const int a_off = (wm + (lane & 15)) * 64 + (lane >> 4) * 16;
  const int b_off = (wn + (lane & 15)) * 68 + (lane >> 4) * 16;
  const int srow = wave * 32 + (lane >> 2);
  const int scol = (lane & 3) * 8;
  const u16* Ab = xT + (long)bb * 524288 + ks * 512;
  const int q = tid & 15, cb = tid >> 4;
  const float* Bbase = U + (long)bb * 16777216 + tn * 128 + cb * 8;
  float4 ca0, ca1, cc0, cc1;
  {
    const float* r0 = Bbase + (long)(ks * 512 + 2 * q) * 4096;
    ca0 = *(const float4*)(r0); ca1 = *(const float4*)(r0 + 4);
    const float* r1 = r0 + 4096;
    cc0 = *(const float4*)(r1); cc1 = *(const float4*)(r1 + 4);
  }
  for (int k0 = 0; k0 < 512; k0 += 32) {
    // A async
#pragma unroll
    for (int i = 0; i < 2; i++)
      gl_lds16(Ab + (long)(srow + i * 16) * 4096 + k0 + scol,
               (char*)As + (wave * 32 + i * 16) * 64);
    // B LDS from prefetched regs
    {
      uint32_t* dw = (uint32_t*)Bs;
      const int base = (cb * 8) * 17 + q;
      dw[base + 0 * 17] = pkbf(ca0.x, cc0.x);
      dw[base + 1 * 17] = pkbf(ca0.y, cc0.y);
      dw[base + 2 * 17] = pkbf(ca0.z, cc0.z);
      dw[base + 3 * 17] = pkbf(ca0.w, cc0.w);
      dw[base + 4 * 17] = pkbf(ca1.x, cc1.x);
      dw[base + 5 * 17] = pkbf(ca1.y, cc1.y);
      dw[base + 6 * 17] = pkbf(ca1.z, cc1.z);
      dw[base + 7 * 17] = pkbf(ca1.w, cc1.w);
    }
    __syncthreads();
    // prefetch next B tile (clamped on last iter)
    const int kn = (k0 + 32 < 512) ? (k0 + 32) : k0;
    float4 na0, na1, nc0, nc1;
    {
      const float* r0 = Bbase + (long)(ks * 512 + kn + 2 * q) * 4096;
      na0 = *(const float4*)(r0); na1 = *(const float4*)(r0 + 4);
      const float* r1 = r0 + 4096;
      nc0 = *(const float4*)(r1); nc1 = *(const float4*)(r1 + 4);
    }
    bf16x8 af[4], bfr[4];
#pragma unroll
    for (int mt = 0; mt < 4; mt++)
      af[mt] = *(const bf16x8*)((const char*)As + a_off + mt * 1024);
#pragma unroll
    for (int nt = 0; nt < 4; nt++)
      bfr[nt] = *(const bf16x8*)((const char*)Bs + b_off + nt * 1088);
#pragma unroll
    for (int mt = 0; mt < 4; mt++)
#pragma unroll
      for (int nt = 0; nt < 4; nt++)
        acc[mt][nt] = __builtin_amdgcn_mfma_f32_16x16x32_bf16(af[mt], bfr[nt], acc[mt][nt], 0, 0, 0);
    __syncthreads();
    ca0 = na0; ca1 = na1; cc0 = nc0; cc1 = nc1;
  }
  // transposed bf16 slice store: xs16[ks][b][n][d]
  const int lr = (lane >> 4) * 4, lc = lane & 15;
  u16* Cf = xs16 + (long)ks * 1048576 + (long)bb * 524288;
#pragma unroll
  for (int mt = 0; mt < 4; mt++)
#pragma unroll
    for (int nt = 0; nt < 4; nt++) {
      const int col = tn * 128 + wn + nt * 16 + lc;
#pragma unroll
      for (int r = 0; r < 4; r++) {
        const int row = wm + mt * 16 + lr + r;
        Cf[(long)col * 128 + row] = f2bf(acc[mt][nt][r]);
      }
    }
}

// ---- reduce 8 bf16 split-K slices, Chebyshev filters -> Mod bf16
__global__ void k_filter(const float* __restrict__ eig, const u16* __restrict__ xs16,
                         const float* __restrict__ coeff, u16* __restrict__ Mod) {
  const int b = blockIdx.y;
  const int n = blockIdx.x * 2 + (threadIdx.x >> 7);
  const int d = threadIdx.x & 127;
  const long ridx = (long)b * 4096 + n;
  const long off = ridx * 128 + d;
  const float e = eig[off];
  float xv = 0.0f;
#pragma unroll
  for (int s = 0; s < 8; s++) xv += bf2f(xs16[off + (long)s * 1048576]);
  const float* cf = coeff + b * 16;
  float To = 1.0f, Tev = e;
  float h = cf[5];
#pragma unroll
  for (int i = 1; i < 5; i++) {
    To = 2.0f * e * Tev - To;
    Tev = 2.0f * e * To - Tev;
    h += cf[5 + i] * To;
  }
  u16* row = Mod + ridx * 768;
  row[d] = f2bf(h * xv);
#pragma unroll
  for (int j = 0; j < 5; j++) {
    const float sx = cf[10 + j] * e;
    float To2 = 1.0f, Te2 = sx;
    float g = cf[0] * Te2;
#pragma unroll
    for (int i = 1; i < 5; i++) {
      To2 = 2.0f * sx * Te2 - To2;
      Te2 = 2.0f * sx * To2 - Te2;
      g += cf[i] * Te2;
    }
    row[(j + 1) * 128 + d] = f2bf(g * xv);
  }
}

// ---- GEMM2: wT[e][m] = sum_k VT[e][k] Mod[m][k]; K=768, bf16 out
__global__ __launch_bounds__(256) void k_gemm2(
    const u16* __restrict__ VT, const u16* __restrict__ Mod, u16* __restrict__ wT) {
  const int tn = blockIdx.x, bb = blockIdx.z;
  __shared__ __align__(16) u16 As[128 * 32];
  __shared__ __align__(16) u16 Bs[128 * 32];
  const int tid = threadIdx.x, wave = tid >> 6, lane = tid & 63;
  const int wm = (wave >> 1) * 64, wn = (wave & 1) * 64;
  f32x4 acc[4][4];
#pragma unroll
  for (int i = 0; i < 4; i++)
#pragma unroll
    for (int j = 0; j < 4; j++)
#pragma unroll
      for (int r = 0; r < 4; r++) acc[i][j][r] = 0.0f;
  const int a_off = (wm + (lane & 15)) * 64 + (lane >> 4) * 16;
  const int b_off = (wn + (lane & 15)) * 64 + (lane >> 4) * 16;
  const int srow = wave * 32 + (lane >> 2);
  const int scol = (lane & 3) * 8;
  const u16* Bb = Mod + (long)bb * 3145728 + (long)tn * 128 * 768;
  for (int k0 = 0; k0 < 768; k0 += 32) {
#pragma unroll
    for (int i = 0; i < 2; i++) {
      gl_lds16(VT + (long)(srow + i * 16) * 768 + k0 + scol,
               (char*)As + (wave * 32 + i * 16) * 64);
      gl_lds16(Bb + (long)(srow + i * 16) * 768 + k0 + scol,
               (char*)Bs + (wave * 32 + i * 16) * 64);
    }
    __syncthreads();
    bf16x8 af[4], bfr[4];
#pragma unroll
    for (int mt = 0; mt < 4; mt++)
      af[mt] = *(const bf16x8*)((const char*)As + a_off + mt * 1024);
#pragma unroll
    for (int nt = 0; nt < 4; nt++)
      bfr[nt] = *(const bf16x8*)((const char*)Bs + b_off + nt * 1024);
#pragma unroll
    for (int mt = 0; mt < 4; mt++)
#pragma unroll
      for (int nt = 0; nt < 4; nt++)
        acc[mt][nt] = __builtin_amdgcn_mfma_f32_16x16x32_bf16(af[mt], bfr[nt], acc[mt][nt], 0, 0, 0);
    __syncthreads();
  }
  const int lr = (lane >> 4) * 4, lc = lane & 15;
  u16* Cb = wT + (long)bb * 524288;
#pragma unroll
  for (int mt = 0; mt < 4; mt++)
#pragma unroll
    for (int nt = 0; nt < 4; nt++) {
      const int col = tn * 128 + wn + nt * 16 + lc;
#pragma unroll
      for (int r = 0; r < 4; r++) {
        const int row = wm + mt * 16 + lr + r;
        Cb[(long)row * 4096 + col] = f2bf(acc[mt][nt][r]);
      }
    }
}

// ---- GEMM3: out[b][n][e] += partial sum_m U[n][m] wT[e][m]  (atomic fp32)
// A = U fp32 rows, register-prefetched; B = wT bf16 via gl_lds.
// d_out pre-initialized with cvec by k_pre.
__global__ __launch_bounds__(256) void k_gemm3(
    const float* __restrict__ U, const u16* __restrict__ wT, float* __restrict__ outp) {
  const int tm = blockIdx.x, ks = blockIdx.y, bb = blockIdx.z;
  __shared__ __align__(16) u16 As[128 * 32];
  __shared__ __align__(16) u16 Bs[128 * 32];
  const int tid = threadIdx.x, wave = tid >> 6, lane = tid & 63;
  const int wm = (wave >> 1) * 64, wn = (wave & 1) * 64;
  f32x4 acc[4][4];
#pragma unroll
  for (int i = 0; i < 4; i++)
#pragma unroll
    for (int j = 0; j < 4; j++)
#pragma unroll
      for (int r = 0; r < 4; r++) acc[i][j][r] = 0.0f;
  const int a_off = (wm + (lane & 15)) * 64 + (lane >> 4) * 16;
  const int b_off = (wn + (lane & 15)) * 64 + (lane >> 4) * 16;
  const int srow = wave * 32 + (lane >> 2);
  const int scol = (lane & 3) * 8;
  const float* Abase = U + (long)bb * 16777216 +
                       (long)(tm * 128 + (tid >> 2)) * 4096 + (tid & 3) * 8;
  const u16* Bb = wT + (long)bb * 524288 + ks * 512;
  float4 cf0, cf1, cg0, cg1;
  {
    const float* s0 = Abase + ks * 512;
    cf0 = *(const float4*)(s0); cf1 = *(const float4*)(s0 + 4);
    const float* s1 = s0 + 262144;
    cg0 = *(const float4*)(s1); cg1 = *(const float4*)(s1 + 4);
  }
  for (int k0 = 0; k0 < 512; k0 += 32) {
    // B async
#pragma unroll
    for (int i = 0; i < 2; i++)
      gl_lds16(Bb + (long)(srow + i * 16) * 4096 + k0 + scol,
               (char*)Bs + (wave * 32 + i * 16) * 64);
    // A LDS from prefetched regs (conflict-free b128)
    *(u32x4*)((char*)As + tid * 16) =
        u32x4{pkbf(cf0.x, cf0.y), pkbf(cf0.z, cf0.w), pkbf(cf1.x, cf1.y), pkbf(cf1.z, cf1.w)};
    *(u32x4*)((char*)As + 4096 + tid * 16) =
        u32x4{pkbf(cg0.x, cg0.y), pkbf(cg0.z, cg0.w), pkbf(cg1.x, cg1.y), pkbf(cg1.z, cg1.w)};
    __syncthreads();
    const int kn = (k0 + 32 < 512) ? (k0 + 32) : k0;
    float4 nf0, nf1, ng0, ng1;
    {
      const float* s0 = Abase + ks * 512 + kn;
      nf0 = *(const float4*)(s0); nf1 = *(const float4*)(s0 + 4);
      const float* s1 = s0 + 262144;
      ng0 = *(const float4*)(s1); ng1 = *(const float4*)(s1 + 4);
    }
    bf16x8 af[4], bfr[4];
#pragma unroll
    for (int mt = 0; mt < 4; mt++)
      af[mt] = *(const bf16x8*)((const char*)As + a_off + mt * 1024);
#pragma unroll
    for (int nt = 0; nt < 4; nt++)
      bfr[nt] = *(const bf16x8*)((const char*)Bs + b_off + nt * 1024);
#pragma unroll
    for (int mt = 0; mt < 4; mt++)
#pragma unroll
      for (int nt = 0; nt < 4; nt++)
        acc[mt][nt] = __builtin_amdgcn_mfma_f32_16x16x32_bf16(af[mt], bfr[nt], acc[mt][nt], 0, 0, 0);
    __syncthreads();
    cf0 = nf0; cf1 = nf1; cg0 = ng0; cg1 = ng1;
  }
  const int lr = (lane >> 4) * 4, lc = lane & 15;
  float* Co = outp + (long)bb * 524288;
#pragma unroll
  for (int mt = 0; mt < 4; mt++)
#pragma unroll
    for (int nt = 0; nt < 4; nt++) {
      const int col = wn + nt * 16 + lc;
#pragma unroll
      for (int r = 0; r < 4; r++) {
        const int row = tm * 128 + wm + mt * 16 + lr + r;
        unsafeAtomicAdd(Co + (long)row * 128 + col, acc[mt][nt][r]);
      }
    }
}

extern "C" void kernel_launch(void* const* d_in, const int* in_sizes, int n_in,
                              void* d_out, int out_size, void* d_ws, size_t ws_size,
                              hipStream_t stream) {
  const float* eig = (const float*)d_in[0];
  const float* x   = (const float*)d_in[1];
  const float* U   = (const float*)d_in[2];
  const float* Wa  = (const float*)d_in[3];
  const float* ba  = (const float*)d_in[4];
  const float* Wb  = (const float*)d_in[5];
  const float* bb  = (const float*)d_in[6];
  const float* Ws  = (const float*)d_in[7];
  const float* bs  = (const float*)d_in[8];
  const float* WSm = (const float*)d_in[9];
  const float* bS  = (const float*)d_in[10];
  const float* WM  = (const float*)d_in[11];
  const float* bM  = (const float*)d_in[12];
  const float* Ww  = (const float*)d_in[13];
  const float* bw  = (const float*)d_in[14];

  char* ws = (char*)d_ws;
  u16*   xs16 = (u16*)(ws + 0);            // 16,777,216 B (8 bf16 split-K slices)
  u16*   Mod  = (u16*)(ws + 16777216);     // 12,582,912 B
  u16*   xT   = (u16*)(ws + 29360128);     //  2,097,152 B
  u16*   wT   = (u16*)(ws + 31457280);     //  2,097,152 B
  u16*   VT   = (u16*)(ws + 33554432);     //    196,608 B
  float* part = (float*)(ws + 33751040);   //     32,768 B
  float* coef = (float*)(ws + 33783808);   //        128 B
  float* outp = (float*)d_out;

  if (ws_size < (size_t)33784064) return;  // workspace guard

  // prolog: eig means + x transpose + VT fold + d_out init with bias vector
  k_pre<<<768, 256, 0, stream>>>(eig, x, WSm, WM, Ww, bS, bM, bw, part, xT, VT, outp);

  // GEMM1 (+ pooled coefficients in tn==32 blocks) -> bf16 slices
  k_gemm1<<<dim3(33, 8, 2), 256, 0, stream>>>(xT, U, part, Wa, ba, Wb, bb, Ws, bs, xs16, coef);

  // slice reduce + Chebyshev filters -> Mod bf16
  k_filter<<<dim3(2048, 2), 256, 0, stream>>>(eig, xs16, coef, Mod);

  // GEMM2
  k_gemm2<<<dim3(32, 1, 2), 256, 0, stream>>>(VT, Mod, wT);

  // GEMM3 -> atomic accumulate into d_out (pre-initialized with cvec)
  k_gemm3<<<dim3(32, 8, 2), 256, 0, stream>>>(U, wT, outp);
}